// Round 11
// baseline (47.833 us; speedup 1.0000x reference)
//
#include <hip/hip_runtime.h>

#define NN 4096
#define TT 365
#define CC 32
#define RPB 4                      // rows per block
#define BLOCK 512                  // 8 waves
#define GRID (NN / RPB)            // 1024 blocks -> 32 waves/CU (8/SIMD)
#define F4_PER_ROW (TT * CC / 4)   // 2920
#define KFULL 5                    // full 512-wide batches per row
#define KTAIL 360                  // 2920 - 5*512
#define LDS_PAD 369

typedef float f32x4 __attribute__((ext_vector_type(4)));

// ws layout (doubles), every location plain-stored each call (no memset):
// [0 .. TT*GRID)       cls partials TRANSPOSED: ws[t*GRID + b]
// [E0 .. E0+GRID)      per-block earliness partials
// [ROW0 .. ROW0+4*NN)  per-row quads: e, e*tf, e*tf^2, (double)label
// [SC]                 scalar (written by stp_scalar, read by stp_out)
#define E0   (TT * GRID)
#define ROW0 (E0 + GRID)
#define SC   (ROW0 + 4 * NN)

__global__ __launch_bounds__(BLOCK, 8) void stp_main(
    const float* __restrict__ logp,   // (N,T,C)
    const float* __restrict__ tl,     // (N,T) -- only column 0 read
    const int*  __restrict__ yt,      // (N,T) -- only column 0 read
    double* __restrict__ ws)
{
    __shared__ float  s_cls[8][LDS_PAD];   // [chunk j][t]; bijective stores
    __shared__ double s_red[BLOCK / 64];

    const int tid = threadIdx.x;
    const int n0  = blockIdx.x * RPB;

    int   lab[RPB], j0[RPB], comp[RPB];
    float tff[RPB];
    const f32x4* row4[RPB];
    #pragma unroll
    for (int r = 0; r < RPB; ++r) {
        const size_t rb = (size_t)(n0 + r) * TT;
        lab[r]  = yt[rb];              // block-uniform
        tff[r]  = tl[rb];              // tl[n,0] = lengths-1 = t_final (exact)
        j0[r]   = lab[r] >> 2;
        comp[r] = lab[r] & 3;
        row4[r] = (const f32x4*)(logp + rb * CC);
    }

    const int j = tid & 7;             // fixed chunk index per thread
    float acc[KFULL + 1] = {0.f, 0.f, 0.f, 0.f, 0.f, 0.f};
    float earl = 0.0f;
    const float invT = 1.0f / 365.0f;

    // rows processed sequentially in address order; NONTEMPORAL loads:
    // read-once stream -> skip cache allocation churn
    for (int r = 0; r < RPB; ++r) {
        const f32x4* rp = row4[r];

        f32x4 v[KFULL + 1];
        #pragma unroll
        for (int k = 0; k <= KFULL; ++k)
            if (k < KFULL || tid < KTAIL)
                v[k] = __builtin_nontemporal_load(rp + tid + k * BLOCK);

        if (j == j0[r]) {              // per-lane ownership (8/64 lanes)
            const int c = comp[r];
            #pragma unroll
            for (int k = 0; k <= KFULL; ++k) {
                if (k < KFULL || tid < KTAIL) {
                    const int   t  = (tid >> 3) + 64 * k;
                    const float tF = (float)t;
                    const float lp = c == 0 ? v[k][0] : c == 1 ? v[k][1]
                                   : c == 2 ? v[k][2] : v[k][3];
                    acc[k] -= lp;
                    const float pc  = __expf(lp);
                    const float tlv = fmaxf(tff[r] - tF, 0.0f);
                    earl += pc * (1.0f - tF * invT) * (1.0f - tlv * invT);
                }
            }
        }
    }

    // single LDS store pass: bijective (j, t) coverage, no init needed
    #pragma unroll
    for (int k = 0; k <= KFULL; ++k)
        if (k < KFULL || tid < KTAIL)
            s_cls[j][(tid >> 3) + 64 * k] = acc[k];

    // per-row stopping-time quad
    if (tid < RPB) {
        const int n = n0 + tid;
        const size_t rb = (size_t)n * TT;
        const int lb = yt[rb];
        const int tf = (int)tl[rb];
        const double e   = (double)__expf(logp[rb * CC + (size_t)tf * CC + lb]);
        const double tfd = (double)tf;
        ws[ROW0 + 4 * n + 0] = e;
        ws[ROW0 + 4 * n + 1] = e * tfd;
        ws[ROW0 + 4 * n + 2] = e * tfd * tfd;
        ws[ROW0 + 4 * n + 3] = (double)lb;
    }

    // earliness block partial: f64 wave reduce -> plain store
    double ed = (double)earl;
    for (int off = 32; off > 0; off >>= 1)
        ed += __shfl_down(ed, off, 64);
    if ((tid & 63) == 0) s_red[tid >> 6] = ed;
    __syncthreads();
    if (tid == 0) {
        double s = 0.0;
        #pragma unroll
        for (int w = 0; w < BLOCK / 64; ++w) s += s_red[w];
        ws[E0 + blockIdx.x] = s;
    }

    // cls block partial -> transposed store (contiguous reads in stp_out)
    if (tid < TT) {
        float s = 0.0f;
        #pragma unroll
        for (int jj = 0; jj < 8; ++jj) s += s_cls[jj][tid];
        ws[(size_t)tid * GRID + blockIdx.x] = (double)s;
    }
}

__global__ __launch_bounds__(512) void stp_scalar(
    double* __restrict__ ws)
{
    __shared__ double sA[CC], sB[CC], sD[CC];
    __shared__ double s_red[8];
    const int tid = threadIdx.x;

    if (tid < CC) { sA[tid] = 0.0; sB[tid] = 0.0; sD[tid] = 0.0; }
    __syncthreads();

    double e = ws[E0 + tid] + ws[E0 + 512 + tid];
    for (int off = 32; off > 0; off >>= 1)
        e += __shfl_down(e, off, 64);
    if ((tid & 63) == 0) s_red[tid >> 6] = e;

    #pragma unroll
    for (int k = 0; k < NN / 512; ++k) {
        const int n = tid + k * 512;
        const double ev = ws[ROW0 + 4 * n + 0];
        const double b  = ws[ROW0 + 4 * n + 1];
        const double d  = ws[ROW0 + 4 * n + 2];
        const int    lb = (int)ws[ROW0 + 4 * n + 3];
        atomicAdd(&sA[lb], ev);
        atomicAdd(&sB[lb], b);
        atomicAdd(&sD[lb], d);
    }
    __syncthreads();

    if (tid == 0) {
        double p = 0.0;
        #pragma unroll
        for (int c = 0; c < CC; ++c)
            p += sA[c] * sD[c] - sB[c] * sB[c];
        p /= (365.0 * 365.0);
        double et = 0.0;
        #pragma unroll
        for (int w = 0; w < 8; ++w) et += s_red[w];
        et /= (double)NN;
        ws[SC] = (1.0 / 3.0) * (et + p);
    }
}

__global__ __launch_bounds__(256) void stp_out(
    const double* __restrict__ ws, float* __restrict__ out)
{
    __shared__ double s_red[4];
    const int t   = blockIdx.x;
    const int tid = threadIdx.x;

    const double* p = ws + (size_t)t * GRID;
    double s = 0.0;
    #pragma unroll
    for (int k = 0; k < GRID / 256; ++k) s += p[tid + k * 256];
    for (int off = 32; off > 0; off >>= 1)
        s += __shfl_down(s, off, 64);
    if ((tid & 63) == 0) s_red[tid >> 6] = s;
    __syncthreads();
    if (tid == 0) {
        double cls = s_red[0] + s_red[1] + s_red[2] + s_red[3];
        out[t] = (float)((1.0 / 3.0) * (cls / (double)NN) - ws[SC]);
    }
}

extern "C" void kernel_launch(void* const* d_in, const int* in_sizes, int n_in,
                              void* d_out, int out_size, void* d_ws, size_t ws_size,
                              hipStream_t stream)
{
    const float* logp = (const float*)d_in[0];
    const float* tl   = (const float*)d_in[1];
    const int*   yt   = (const int*)d_in[2];
    float* out = (float*)d_out;
    double* ws = (double*)d_ws;

    stp_main<<<GRID, BLOCK, 0, stream>>>(logp, tl, yt, ws);
    stp_scalar<<<1, 512, 0, stream>>>(ws);
    stp_out<<<TT, 256, 0, stream>>>(ws, out);
}

// Round 12
// 44.581 us; speedup vs baseline: 1.0730x; 1.0730x over previous
//
#include <hip/hip_runtime.h>

#define NN 4096
#define TT 365
#define CC 32
#define RPB 4                      // rows per block
#define BLOCK 512                  // 8 waves
#define GRID (NN / RPB)            // 1024 blocks -> 32 waves/CU (8/SIMD)
#define F4_PER_ROW (TT * CC / 4)   // 2920
#define KFULL 5                    // full 512-wide batches per row
#define KTAIL 360                  // 2920 - 5*512
#define LDS_PAD 369

// ws layout (doubles), every location plain-stored each call (no memset):
// [0 .. TT*GRID)       cls partials TRANSPOSED: ws[t*GRID + b]
// [E0 .. E0+GRID)      per-block earliness partials
// [ROW0 .. ROW0+4*NN)  per-row quads: e, e*tf, e*tf^2, (double)label
// [SC]                 scalar (written by stp_scalar, read by stp_out)
#define E0   (TT * GRID)
#define ROW0 (E0 + GRID)
#define SC   (ROW0 + 4 * NN)

__global__ __launch_bounds__(BLOCK, 8) void stp_main(
    const float* __restrict__ logp,   // (N,T,C)
    const float* __restrict__ tl,     // (N,T) -- only column 0 read
    const int*  __restrict__ yt,      // (N,T) -- only column 0 read
    double* __restrict__ ws)
{
    __shared__ float  s_cls[8][LDS_PAD];   // [chunk j][t]; bijective stores
    __shared__ double s_red[BLOCK / 64];

    const int tid = threadIdx.x;
    const int n0  = blockIdx.x * RPB;

    int   lab[RPB], j0[RPB], comp[RPB];
    float tff[RPB];
    const float4* row4[RPB];
    #pragma unroll
    for (int r = 0; r < RPB; ++r) {
        const size_t rb = (size_t)(n0 + r) * TT;
        lab[r]  = yt[rb];              // block-uniform
        tff[r]  = tl[rb];              // tl[n,0] = lengths-1 = t_final (exact)
        j0[r]   = lab[r] >> 2;
        comp[r] = lab[r] & 3;
        row4[r] = (const float4*)(logp + rb * CC);
    }

    const int j = tid & 7;             // fixed chunk index per thread
    float acc[KFULL + 1] = {0.f, 0.f, 0.f, 0.f, 0.f, 0.f};
    float earl = 0.0f;
    const float invT = 1.0f / 365.0f;

    // rows processed sequentially in address order (block region contiguous)
    for (int r = 0; r < RPB; ++r) {
        const float4* rp = row4[r];

        float4 v[KFULL + 1];
        #pragma unroll
        for (int k = 0; k <= KFULL; ++k)
            if (k < KFULL || tid < KTAIL) v[k] = rp[tid + k * BLOCK];

        if (j == j0[r]) {              // per-lane ownership (8/64 lanes)
            const int c = comp[r];
            #pragma unroll
            for (int k = 0; k <= KFULL; ++k) {
                if (k < KFULL || tid < KTAIL) {
                    const int   t  = (tid >> 3) + 64 * k;
                    const float tF = (float)t;
                    const float lp = c == 0 ? v[k].x : c == 1 ? v[k].y
                                   : c == 2 ? v[k].z : v[k].w;
                    acc[k] -= lp;
                    const float pc  = __expf(lp);
                    const float tlv = fmaxf(tff[r] - tF, 0.0f);
                    earl += pc * (1.0f - tF * invT) * (1.0f - tlv * invT);
                }
            }
        }
    }

    // single LDS store pass: bijective (j, t) coverage, no init needed
    #pragma unroll
    for (int k = 0; k <= KFULL; ++k)
        if (k < KFULL || tid < KTAIL)
            s_cls[j][(tid >> 3) + 64 * k] = acc[k];

    // per-row stopping-time quad (line is cache-hot from the stream)
    if (tid < RPB) {
        const int n = n0 + tid;
        const size_t rb = (size_t)n * TT;
        const int lb = yt[rb];
        const int tf = (int)tl[rb];
        const double e   = (double)__expf(logp[rb * CC + (size_t)tf * CC + lb]);
        const double tfd = (double)tf;
        ws[ROW0 + 4 * n + 0] = e;
        ws[ROW0 + 4 * n + 1] = e * tfd;
        ws[ROW0 + 4 * n + 2] = e * tfd * tfd;
        ws[ROW0 + 4 * n + 3] = (double)lb;
    }

    // earliness block partial: f64 wave reduce -> plain store
    double ed = (double)earl;
    for (int off = 32; off > 0; off >>= 1)
        ed += __shfl_down(ed, off, 64);
    if ((tid & 63) == 0) s_red[tid >> 6] = ed;
    __syncthreads();
    if (tid == 0) {
        double s = 0.0;
        #pragma unroll
        for (int w = 0; w < BLOCK / 64; ++w) s += s_red[w];
        ws[E0 + blockIdx.x] = s;
    }

    // cls block partial -> transposed store (contiguous reads in stp_out)
    if (tid < TT) {
        float s = 0.0f;
        #pragma unroll
        for (int jj = 0; jj < 8; ++jj) s += s_cls[jj][tid];
        ws[(size_t)tid * GRID + blockIdx.x] = (double)s;
    }
}

__global__ __launch_bounds__(512) void stp_scalar(
    double* __restrict__ ws)
{
    __shared__ double sA[CC], sB[CC], sD[CC];
    __shared__ double s_red[8];
    const int tid = threadIdx.x;

    if (tid < CC) { sA[tid] = 0.0; sB[tid] = 0.0; sD[tid] = 0.0; }
    __syncthreads();

    double e = ws[E0 + tid] + ws[E0 + 512 + tid];
    for (int off = 32; off > 0; off >>= 1)
        e += __shfl_down(e, off, 64);
    if ((tid & 63) == 0) s_red[tid >> 6] = e;

    #pragma unroll
    for (int k = 0; k < NN / 512; ++k) {
        const int n = tid + k * 512;
        const double ev = ws[ROW0 + 4 * n + 0];
        const double b  = ws[ROW0 + 4 * n + 1];
        const double d  = ws[ROW0 + 4 * n + 2];
        const int    lb = (int)ws[ROW0 + 4 * n + 3];
        atomicAdd(&sA[lb], ev);
        atomicAdd(&sB[lb], b);
        atomicAdd(&sD[lb], d);
    }
    __syncthreads();

    if (tid == 0) {
        double p = 0.0;
        #pragma unroll
        for (int c = 0; c < CC; ++c)
            p += sA[c] * sD[c] - sB[c] * sB[c];
        p /= (365.0 * 365.0);
        double et = 0.0;
        #pragma unroll
        for (int w = 0; w < 8; ++w) et += s_red[w];
        et /= (double)NN;
        ws[SC] = (1.0 / 3.0) * (et + p);
    }
}

__global__ __launch_bounds__(256) void stp_out(
    const double* __restrict__ ws, float* __restrict__ out)
{
    __shared__ double s_red[4];
    const int t   = blockIdx.x;
    const int tid = threadIdx.x;

    const double* p = ws + (size_t)t * GRID;
    double s = 0.0;
    #pragma unroll
    for (int k = 0; k < GRID / 256; ++k) s += p[tid + k * 256];
    for (int off = 32; off > 0; off >>= 1)
        s += __shfl_down(s, off, 64);
    if ((tid & 63) == 0) s_red[tid >> 6] = s;
    __syncthreads();
    if (tid == 0) {
        double cls = s_red[0] + s_red[1] + s_red[2] + s_red[3];
        out[t] = (float)((1.0 / 3.0) * (cls / (double)NN) - ws[SC]);
    }
}

extern "C" void kernel_launch(void* const* d_in, const int* in_sizes, int n_in,
                              void* d_out, int out_size, void* d_ws, size_t ws_size,
                              hipStream_t stream)
{
    const float* logp = (const float*)d_in[0];
    const float* tl   = (const float*)d_in[1];
    const int*   yt   = (const int*)d_in[2];
    float* out = (float*)d_out;
    double* ws = (double*)d_ws;

    stp_main<<<GRID, BLOCK, 0, stream>>>(logp, tl, yt, ws);
    stp_scalar<<<1, 512, 0, stream>>>(ws);
    stp_out<<<TT, 256, 0, stream>>>(ws, out);
}